// Round 10
// baseline (2973.002 us; speedup 1.0000x reference)
//
#include <hip/hip_runtime.h>
#include <hip/hip_bf16.h>

// Problem constants
// B=8, N=8192, NPOINT=2048, NSAMPLE=16, CIN=22, COUT=64
// outputs: [B,3,2048] (49152) | [B,192,2048] (3145728) | [B,2048] fps idx as float (16384)

typedef float v2f __attribute__((ext_vector_type(2)));
typedef unsigned long long ull;

// ---------------------------------------------------------------------------
// Kernel 1: furthest point sampling. One block per batch, exact NumPy-order
// f32 arithmetic (no FMA contraction) so every argmax matches the reference.
// v4: 256 threads (4 waves = 1 wave/SIMD), 32 pts/thread. Structure per iter:
// packed dmin update + running max, u32 DPP max chain on dist bits,
// readlane(63) broadcast, winner-lane rescan + ONE LDS ds_max_u64 atomic
// (iteration-tagged self-resetting key), ONE barrier.
// Ties -> max(8191-idx) = min idx = np.argmax first-occurrence.
// ---------------------------------------------------------------------------
__global__ __launch_bounds__(256) void fps_kernel(
    const float* __restrict__ xyz, int* __restrict__ fps_ws,
    float* __restrict__ nxyz_ws, float* __restrict__ d2_ws,
    float* __restrict__ out0, float* __restrict__ out2) {
#pragma clang fp contract(off)
  const int b = blockIdx.x;
  const int t = threadIdx.x;
  __shared__ float lx[8192], ly[8192], lz[8192];
  __shared__ ull kslot[2];
  __shared__ int hist[2048];
  const float* xb = xyz + (size_t)b * 3 * 8192;

  v2f px[16], py[16], pz[16], dmin[16];
#pragma unroll
  for (int j = 0; j < 16; ++j) {
    int n = j * 512 + 2 * t;
    px[j] = *(const v2f*)&xb[n];
    py[j] = *(const v2f*)&xb[8192 + n];
    pz[j] = *(const v2f*)&xb[16384 + n];
    dmin[j] = (v2f){1e10f, 1e10f};
    lx[n] = px[j].x; lx[n + 1] = px[j].y;
    ly[n] = py[j].x; ly[n + 1] = py[j].y;
    lz[n] = pz[j].x; lz[n + 1] = pz[j].y;
    // squared norms for the KNN kernel (exactness not critical there)
    v2f sx = px[j] * px[j], sy = py[j] * py[j], sz = pz[j] * pz[j];
    v2f d2 = (sx + sy) + sz;
    *(v2f*)&d2_ws[b * 8192 + n] = d2;
  }
  if (t == 0) { kslot[0] = 0; kslot[1] = 0; }
  int cur = 0;
  __syncthreads();

  for (int it = 0; it < 2048; ++it) {
    float cx = lx[cur], cy = ly[cur], cz = lz[cur];
    if (t == 0) hist[it] = cur;
    v2f bv2 = (v2f){-1.0f, -1.0f};
#pragma unroll
    for (int j = 0; j < 16; ++j) {
      v2f dx = px[j] - cx, dy = py[j] - cy, dz = pz[j] - cz;
      v2f sq = (dx * dx + dy * dy) + dz * dz;  // ((dx^2+dy^2)+dz^2), no FMA
      v2f dm = dmin[j];
      dm.x = fminf(dm.x, sq.x);
      dm.y = fminf(dm.y, sq.y);
      dmin[j] = dm;
      bv2.x = fmaxf(bv2.x, dm.x);
      bv2.y = fmaxf(bv2.y, dm.y);
    }
    float bv = fmaxf(bv2.x, bv2.y);
    unsigned ub = __float_as_uint(bv);  // dist>=0: u32 order == f32 order
    // wave-wide u32 max via DPP (row_shr 1/2/4/8, row_bcast15/31), ans @ lane63
    unsigned m = ub;
#define DPP_U32MAX(ctrl)                                                            \
    {                                                                               \
      unsigned o = (unsigned)__builtin_amdgcn_update_dpp((int)m, (int)m, ctrl, 0xF, 0xF, false); \
      m = (o > m) ? o : m;                                                          \
    }
    DPP_U32MAX(0x111)
    DPP_U32MAX(0x112)
    DPP_U32MAX(0x114)
    DPP_U32MAX(0x118)
    DPP_U32MAX(0x142)
    DPP_U32MAX(0x143)
#undef DPP_U32MAX
    unsigned W = (unsigned)__builtin_amdgcn_readlane((int)m, 63);
    if (ub == W) {
      // winner lane(s): first (lowest) global idx among this thread's 32
      int bn = 0;
#pragma unroll
      for (int j = 15; j >= 0; --j) {
        int n = j * 512 + 2 * t;
        if (dmin[j].y == bv) bn = n + 1;
        if (dmin[j].x == bv) bn = n;
      }
      ull key = ((ull)(unsigned)(it + 1) << 45) | ((ull)ub << 13) |
                (unsigned)(8191 - bn);
      atomicMax(&kslot[it & 1], key);
    }
    __syncthreads();
    ull g = kslot[it & 1];
    cur = 8191 - (int)((unsigned)g & 0x1FFFu);
  }
  __syncthreads();

  // epilogue: write all outputs from LDS history
  for (int i = t; i < 2048; i += 256) {
    int idx = hist[i];
    float cx = lx[idx], cy = ly[idx], cz = lz[idx];
    fps_ws[b * 2048 + i] = idx;
    out2[b * 2048 + i] = (float)idx;
    out0[(b * 3 + 0) * 2048 + i] = cx;
    out0[(b * 3 + 1) * 2048 + i] = cy;
    out0[(b * 3 + 2) * 2048 + i] = cz;
    nxyz_ws[(b * 2048 + i) * 3 + 0] = cx;
    nxyz_ws[(b * 2048 + i) * 3 + 1] = cy;
    nxyz_ws[(b * 2048 + i) * 3 + 2] = cz;
  }
}

// ---------------------------------------------------------------------------
// Kernel 2: 16-NN per sampled point. One wave per query; per-lane sorted
// top-16 of 64-bit keys (dist_bits<<32 | idx), then wave-min merge.
// ---------------------------------------------------------------------------
__global__ __launch_bounds__(256) void knn_kernel(
    const float* __restrict__ xyz, const float* __restrict__ nxyz_ws,
    const float* __restrict__ d2_ws, int* __restrict__ knn_ws) {
  const int qid = blockIdx.x * 4 + (threadIdx.x >> 6);
  const int lane = threadIdx.x & 63;
  const int b = qid >> 11;
  const float qx = nxyz_ws[qid * 3], qy = nxyz_ws[qid * 3 + 1], qz = nxyz_ws[qid * 3 + 2];
  const float s2q = qx * qx + qy * qy + qz * qz;
  const float* xb = xyz + (size_t)b * 24576;
  const float* d2b = d2_ws + b * 8192;
  ull arr[16];
#pragma unroll
  for (int j = 0; j < 16; ++j) arr[j] = ~0ull;

  for (int c0 = 0; c0 < 8192; c0 += 64) {
    int n = c0 + lane;
    float x = xb[n], y = xb[8192 + n], z = xb[16384 + n];
    float d2v = d2b[n];
    float dot = qx * x + qy * y + qz * z;
    float dist = (s2q + d2v) - 2.0f * dot;
    unsigned u = __float_as_uint(dist);
    u ^= (unsigned)((int)u >> 31) | 0x80000000u;  // order-preserving flip
    ull key = ((ull)u << 32) | (unsigned)n;
    if (key < arr[15]) {
#pragma unroll
      for (int j = 15; j >= 1; --j)
        arr[j] = (key < arr[j - 1]) ? arr[j - 1] : (arr[j] < key ? arr[j] : key);
      arr[0] = arr[0] < key ? arr[0] : key;
    }
  }
  const int obase = qid * 16;
#pragma unroll 1
  for (int r = 0; r < 16; ++r) {
    ull m = arr[0];
#pragma unroll
    for (int off = 1; off < 64; off <<= 1) {
      ull o = __shfl_xor(m, off);
      m = o < m ? o : m;
    }
    if (lane == r) knn_ws[obase + r] = (int)(unsigned)(m & 0xFFFFFFFFull);
    bool win = (arr[0] == m);
#pragma unroll
    for (int j = 0; j < 15; ++j) arr[j] = win ? arr[j + 1] : arr[j];
    arr[15] = win ? ~0ull : arr[15];
  }
}

// ---------------------------------------------------------------------------
// Kernel 3: fused gather + VNLinearLeakyReLU + VNMaxPool.
// v2: 8 query-points (s) per block -> weights staged ONCE per 8 s
// (was: once per s; 7/8 of the global weight traffic + a barrier removed).
// 256 threads; thread -> (co = t>>2, k-quad = t&3). f32 VALU throughout.
// LDS layout (floats), padded for bank-conflict freedom:
//   wf[64*22] @0, wd @1408, wp[64*65] @2816, x[22*52] @6976,
//   xo[64*52] @8120, sc[64*16] @11448   (total 12472 floats ~ 48.7 KB)
// ---------------------------------------------------------------------------
#define WFo 0
#define WDo 1408
#define WPo 2816
#define Xo 6976
#define XOo 8120
#define SCo 11448
#define SMEM_F 12472

__global__ __launch_bounds__(256) void vn_kernel(
    const float* __restrict__ xyz, const float* __restrict__ points,
    const float* __restrict__ w_feat, const float* __restrict__ w_dir,
    const float* __restrict__ w_pool, const float* __restrict__ nxyz_ws,
    const int* __restrict__ knn_ws, float* __restrict__ out1) {
  __shared__ __align__(16) float sm[SMEM_F];
  __shared__ int ki[8][16];
  __shared__ float q[8][3];
  const int bs0 = blockIdx.x * 8;   // first of 8 consecutive (b,s) units
  const int b = bs0 >> 11;
  const int t = threadIdx.x;

  for (int i = t; i < 1408; i += 256) {
    sm[WFo + i] = w_feat[i];
    sm[WDo + i] = w_dir[i];
  }
  for (int i = t; i < 4096; i += 256) sm[WPo + (i >> 6) * 65 + (i & 63)] = w_pool[i];
  if (t < 128) ki[t >> 4][t & 15] = knn_ws[(bs0 + (t >> 4)) * 16 + (t & 15)];
  if (t < 24) q[t / 3][t % 3] = nxyz_ws[bs0 * 3 + t];
  __syncthreads();

  const int co = t >> 2, kq = t & 3;

  for (int si = 0; si < 8; ++si) {
    const int s = (bs0 + si) & 2047;
    // gather -> x[c][v][k]  (c=0: grouped_xyz - new_xyz; c>=1: points channels)
    for (int e = t; e < 1056; e += 256) {
      int k = e & 15, f = e >> 4;
      int c = f / 3, v = f - 3 * c;
      int n = ki[si][k];
      float val;
      if (c == 0)
        val = xyz[((size_t)b * 3 + v) * 8192 + n] - q[si][v];
      else
        val = points[((size_t)b * 63 + 3 * (c - 1) + v) * 8192 + n];
      sm[Xo + c * 52 + v * 16 + k] = val;
    }
    __syncthreads();

    float P[3][4] = {{0}}, D[3][4] = {{0}};
    for (int c = 0; c < 22; ++c) {
      float wfv = sm[WFo + co * 22 + c];
      float wdv = sm[WDo + co * 22 + c];
#pragma unroll
      for (int v = 0; v < 3; ++v) {
        float4 xv = *(const float4*)&sm[Xo + c * 52 + v * 16 + kq * 4];
        P[v][0] += wfv * xv.x; P[v][1] += wfv * xv.y; P[v][2] += wfv * xv.z; P[v][3] += wfv * xv.w;
        D[v][0] += wdv * xv.x; D[v][1] += wdv * xv.y; D[v][2] += wdv * xv.z; D[v][3] += wdv * xv.w;
      }
    }
    float XO_[3][4];
#pragma unroll
    for (int kk = 0; kk < 4; ++kk) {
      float dot = P[0][kk] * D[0][kk] + P[1][kk] * D[1][kk] + P[2][kk] * D[2][kk];
      float dsq = D[0][kk] * D[0][kk] + D[1][kk] * D[1][kk] + D[2][kk] * D[2][kk];
      float tc = dot / (dsq + 1e-6f);
#pragma unroll
      for (int v = 0; v < 3; ++v) {
        float pv = P[v][kk], dv = D[v][kk];
        float wv = (dot >= 0.f) ? pv : (pv - tc * dv);
        XO_[v][kk] = 0.2f * pv + 0.8f * wv;
      }
    }
#pragma unroll
    for (int v = 0; v < 3; ++v)
      *(float4*)&sm[XOo + co * 52 + v * 16 + kq * 4] =
          make_float4(XO_[v][0], XO_[v][1], XO_[v][2], XO_[v][3]);
    __syncthreads();

    float dp[3][4] = {{0}};
    for (int c2 = 0; c2 < 64; ++c2) {
      float wpv = sm[WPo + co * 65 + c2];
#pragma unroll
      for (int v = 0; v < 3; ++v) {
        float4 xv = *(const float4*)&sm[XOo + c2 * 52 + v * 16 + kq * 4];
        dp[v][0] += wpv * xv.x; dp[v][1] += wpv * xv.y; dp[v][2] += wpv * xv.z; dp[v][3] += wpv * xv.w;
      }
    }
    float4 sc4;
    sc4.x = XO_[0][0] * dp[0][0] + XO_[1][0] * dp[1][0] + XO_[2][0] * dp[2][0];
    sc4.y = XO_[0][1] * dp[0][1] + XO_[1][1] * dp[1][1] + XO_[2][1] * dp[2][1];
    sc4.z = XO_[0][2] * dp[0][2] + XO_[1][2] * dp[1][2] + XO_[2][2] * dp[2][2];
    sc4.w = XO_[0][3] * dp[0][3] + XO_[1][3] * dp[1][3] + XO_[2][3] * dp[2][3];
    *(float4*)&sm[SCo + co * 16 + kq * 4] = sc4;
    __syncthreads();

    if (t < 64) {
      int coo = t;
      float best = sm[SCo + coo * 16];
      int bk = 0;
#pragma unroll
      for (int k = 1; k < 16; ++k) {
        float v = sm[SCo + coo * 16 + k];
        if (v > best) { best = v; bk = k; }  // strict > keeps first index (np.argmax)
      }
#pragma unroll
      for (int v = 0; v < 3; ++v)
        out1[((size_t)(b * 192 + coo * 3 + v)) * 2048 + s] = sm[XOo + coo * 52 + v * 16 + bk];
    }
    __syncthreads();  // protect Xo/XOo/sc before next si overwrites
  }
}

// ---------------------------------------------------------------------------
extern "C" void kernel_launch(void* const* d_in, const int* in_sizes, int n_in,
                              void* d_out, int out_size, void* d_ws, size_t ws_size,
                              hipStream_t stream) {
  const float* xyz = (const float*)d_in[0];     // [8,3,8192]
  const float* points = (const float*)d_in[1];  // [8,63,8192]
  const float* w_feat = (const float*)d_in[2];  // [64,22]
  const float* w_dir = (const float*)d_in[3];   // [64,22]
  const float* w_pool = (const float*)d_in[4];  // [64,64]

  float* out = (float*)d_out;
  float* out0 = out;             // [8,3,2048]
  float* out1 = out + 49152;     // [8,192,2048]
  float* out2 = out + 3194880;   // [8,2048] fps idx as float

  char* ws = (char*)d_ws;
  int* fps_ws = (int*)ws;                   // 16384 ints
  float* nxyz_ws = (float*)(ws + 65536);    // 49152 floats  [B,S,3]
  float* d2_ws = (float*)(ws + 262144);     // 65536 floats  [B,N]
  int* knn_ws = (int*)(ws + 524288);        // 262144 ints   [B,S,16]

  fps_kernel<<<8, 256, 0, stream>>>(xyz, fps_ws, nxyz_ws, d2_ws, out0, out2);
  knn_kernel<<<4096, 256, 0, stream>>>(xyz, nxyz_ws, d2_ws, knn_ws);
  vn_kernel<<<2048, 256, 0, stream>>>(xyz, points, w_feat, w_dir, w_pool, nxyz_ws,
                                      knn_ws, out1);
}

// Round 13
// 2597.774 us; speedup vs baseline: 1.1444x; 1.1444x over previous
//
#include <hip/hip_runtime.h>
#include <hip/hip_bf16.h>

// Problem constants
// B=8, N=8192, NPOINT=2048, NSAMPLE=16, CIN=22, COUT=64
// outputs: [B,3,2048] (49152) | [B,192,2048] (3145728) | [B,2048] fps idx as float (16384)

typedef float v2f __attribute__((ext_vector_type(2)));
typedef unsigned long long ull;

// ---------------------------------------------------------------------------
// Kernel 1: furthest point sampling. One block per batch, exact NumPy-order
// f32 arithmetic (no FMA contraction) so every argmax matches the reference.
// v5: 1024 threads (16 waves = 4/SIMD), 8 pts/thread. R10 showed the serial
// reduction tail (DPP+atomic+barrier+LDS read) hides under sibling waves'
// compute on the same SIMD: 1 wave/SIMD = no hiding (2131 us), 2/SIMD =
// partial (1884 us). 4/SIMD maximizes tail overlap at constant per-SIMD
// compute issue time. Per iter: packed dmin update + running max, u32 DPP
// max chain on dist bits, readlane(63), winner-lane rescan + ONE LDS
// ds_max_u64 atomic (iteration-tagged self-resetting key), ONE barrier.
// Ties -> max(8191-idx) = min idx = np.argmax first-occurrence.
// ---------------------------------------------------------------------------
__global__ __launch_bounds__(1024) void fps_kernel(
    const float* __restrict__ xyz, int* __restrict__ fps_ws,
    float* __restrict__ nxyz_ws, float* __restrict__ d2_ws,
    float* __restrict__ out0, float* __restrict__ out2) {
#pragma clang fp contract(off)
  const int b = blockIdx.x;
  const int t = threadIdx.x;
  __shared__ float lx[8192], ly[8192], lz[8192];
  __shared__ ull kslot[2];
  __shared__ int hist[2048];
  const float* xb = xyz + (size_t)b * 3 * 8192;

  v2f px[4], py[4], pz[4], dmin[4];
#pragma unroll
  for (int j = 0; j < 4; ++j) {
    int n = j * 2048 + 2 * t;
    px[j] = *(const v2f*)&xb[n];
    py[j] = *(const v2f*)&xb[8192 + n];
    pz[j] = *(const v2f*)&xb[16384 + n];
    dmin[j] = (v2f){1e10f, 1e10f};
    lx[n] = px[j].x; lx[n + 1] = px[j].y;
    ly[n] = py[j].x; ly[n + 1] = py[j].y;
    lz[n] = pz[j].x; lz[n + 1] = pz[j].y;
    // squared norms for the KNN kernel (exactness not critical there)
    v2f sx = px[j] * px[j], sy = py[j] * py[j], sz = pz[j] * pz[j];
    v2f d2 = (sx + sy) + sz;
    *(v2f*)&d2_ws[b * 8192 + n] = d2;
  }
  if (t == 0) { kslot[0] = 0; kslot[1] = 0; }
  int cur = 0;
  __syncthreads();

  for (int it = 0; it < 2048; ++it) {
    float cx = lx[cur], cy = ly[cur], cz = lz[cur];
    if (t == 0) hist[it] = cur;
    v2f bv2 = (v2f){-1.0f, -1.0f};
#pragma unroll
    for (int j = 0; j < 4; ++j) {
      v2f dx = px[j] - cx, dy = py[j] - cy, dz = pz[j] - cz;
      v2f sq = (dx * dx + dy * dy) + dz * dz;  // ((dx^2+dy^2)+dz^2), no FMA
      v2f dm = dmin[j];
      dm.x = fminf(dm.x, sq.x);
      dm.y = fminf(dm.y, sq.y);
      dmin[j] = dm;
      bv2.x = fmaxf(bv2.x, dm.x);
      bv2.y = fmaxf(bv2.y, dm.y);
    }
    float bv = fmaxf(bv2.x, bv2.y);
    unsigned ub = __float_as_uint(bv);  // dist>=0: u32 order == f32 order
    // wave-wide u32 max via DPP (row_shr 1/2/4/8, row_bcast15/31), ans @ lane63
    unsigned m = ub;
#define DPP_U32MAX(ctrl)                                                            \
    {                                                                               \
      unsigned o = (unsigned)__builtin_amdgcn_update_dpp((int)m, (int)m, ctrl, 0xF, 0xF, false); \
      m = (o > m) ? o : m;                                                          \
    }
    DPP_U32MAX(0x111)
    DPP_U32MAX(0x112)
    DPP_U32MAX(0x114)
    DPP_U32MAX(0x118)
    DPP_U32MAX(0x142)
    DPP_U32MAX(0x143)
#undef DPP_U32MAX
    unsigned W = (unsigned)__builtin_amdgcn_readlane((int)m, 63);
    if (ub == W) {
      // winner lane(s): first (lowest) global idx among this thread's 8
      int bn = 0;
#pragma unroll
      for (int j = 3; j >= 0; --j) {
        int n = j * 2048 + 2 * t;
        if (dmin[j].y == bv) bn = n + 1;
        if (dmin[j].x == bv) bn = n;
      }
      ull key = ((ull)(unsigned)(it + 1) << 45) | ((ull)ub << 13) |
                (unsigned)(8191 - bn);
      atomicMax(&kslot[it & 1], key);
    }
    __syncthreads();
    ull g = kslot[it & 1];
    cur = 8191 - (int)((unsigned)g & 0x1FFFu);
  }
  __syncthreads();

  // epilogue: write all outputs from LDS history
  for (int i = t; i < 2048; i += 1024) {
    int idx = hist[i];
    float cx = lx[idx], cy = ly[idx], cz = lz[idx];
    fps_ws[b * 2048 + i] = idx;
    out2[b * 2048 + i] = (float)idx;
    out0[(b * 3 + 0) * 2048 + i] = cx;
    out0[(b * 3 + 1) * 2048 + i] = cy;
    out0[(b * 3 + 2) * 2048 + i] = cz;
    nxyz_ws[(b * 2048 + i) * 3 + 0] = cx;
    nxyz_ws[(b * 2048 + i) * 3 + 1] = cy;
    nxyz_ws[(b * 2048 + i) * 3 + 2] = cz;
  }
}

// ---------------------------------------------------------------------------
// Kernel 2: 16-NN per sampled point. One wave per query; per-lane sorted
// top-16 of 64-bit keys (dist_bits<<32 | idx), then wave-min merge.
// ---------------------------------------------------------------------------
__global__ __launch_bounds__(256) void knn_kernel(
    const float* __restrict__ xyz, const float* __restrict__ nxyz_ws,
    const float* __restrict__ d2_ws, int* __restrict__ knn_ws) {
  const int qid = blockIdx.x * 4 + (threadIdx.x >> 6);
  const int lane = threadIdx.x & 63;
  const int b = qid >> 11;
  const float qx = nxyz_ws[qid * 3], qy = nxyz_ws[qid * 3 + 1], qz = nxyz_ws[qid * 3 + 2];
  const float s2q = qx * qx + qy * qy + qz * qz;
  const float* xb = xyz + (size_t)b * 24576;
  const float* d2b = d2_ws + b * 8192;
  ull arr[16];
#pragma unroll
  for (int j = 0; j < 16; ++j) arr[j] = ~0ull;

  for (int c0 = 0; c0 < 8192; c0 += 64) {
    int n = c0 + lane;
    float x = xb[n], y = xb[8192 + n], z = xb[16384 + n];
    float d2v = d2b[n];
    float dot = qx * x + qy * y + qz * z;
    float dist = (s2q + d2v) - 2.0f * dot;
    unsigned u = __float_as_uint(dist);
    u ^= (unsigned)((int)u >> 31) | 0x80000000u;  // order-preserving flip
    ull key = ((ull)u << 32) | (unsigned)n;
    if (key < arr[15]) {
#pragma unroll
      for (int j = 15; j >= 1; --j)
        arr[j] = (key < arr[j - 1]) ? arr[j - 1] : (arr[j] < key ? arr[j] : key);
      arr[0] = arr[0] < key ? arr[0] : key;
    }
  }
  const int obase = qid * 16;
#pragma unroll 1
  for (int r = 0; r < 16; ++r) {
    ull m = arr[0];
#pragma unroll
    for (int off = 1; off < 64; off <<= 1) {
      ull o = __shfl_xor(m, off);
      m = o < m ? o : m;
    }
    if (lane == r) knn_ws[obase + r] = (int)(unsigned)(m & 0xFFFFFFFFull);
    bool win = (arr[0] == m);
#pragma unroll
    for (int j = 0; j < 15; ++j) arr[j] = win ? arr[j + 1] : arr[j];
    arr[15] = win ? ~0ull : arr[15];
  }
}

// ---------------------------------------------------------------------------
// Kernel 3: fused gather + VNLinearLeakyReLU + VNMaxPool per (b,s).
// 256 threads; thread -> (co = t>>2, k-quad = t&3). f32 VALU throughout.
// LDS layout (floats), padded for bank-conflict freedom:
//   wf[64*22] @0, wd @1408, wp[64*65] @2816, x[22*52] @6976,
//   xo[64*52] @8120, sc[64*16] @11448   (total 12472 floats ~ 48.7 KB)
// ---------------------------------------------------------------------------
#define WFo 0
#define WDo 1408
#define WPo 2816
#define Xo 6976
#define XOo 8120
#define SCo 11448
#define SMEM_F 12472

__global__ __launch_bounds__(256) void vn_kernel(
    const float* __restrict__ xyz, const float* __restrict__ points,
    const float* __restrict__ w_feat, const float* __restrict__ w_dir,
    const float* __restrict__ w_pool, const float* __restrict__ nxyz_ws,
    const int* __restrict__ knn_ws, float* __restrict__ out1) {
  __shared__ __align__(16) float sm[SMEM_F];
  __shared__ int ki[16];
  __shared__ float q[3];
  const int bs = blockIdx.x;
  const int b = bs >> 11, s = bs & 2047;
  const int t = threadIdx.x;

  for (int i = t; i < 1408; i += 256) {
    sm[WFo + i] = w_feat[i];
    sm[WDo + i] = w_dir[i];
  }
  for (int i = t; i < 4096; i += 256) sm[WPo + (i >> 6) * 65 + (i & 63)] = w_pool[i];
  if (t < 16) ki[t] = knn_ws[bs * 16 + t];
  if (t < 3) q[t] = nxyz_ws[bs * 3 + t];
  __syncthreads();

  // gather -> x[c][v][k]  (c=0: grouped_xyz - new_xyz; c>=1: points channels)
  for (int e = t; e < 1056; e += 256) {
    int k = e & 15, f = e >> 4;
    int c = f / 3, v = f - 3 * c;
    int n = ki[k];
    float val;
    if (c == 0)
      val = xyz[((size_t)b * 3 + v) * 8192 + n] - q[v];
    else
      val = points[((size_t)b * 63 + 3 * (c - 1) + v) * 8192 + n];
    sm[Xo + c * 52 + v * 16 + k] = val;
  }
  __syncthreads();

  const int co = t >> 2, kq = t & 3;
  float P[3][4] = {{0}}, D[3][4] = {{0}};
  for (int c = 0; c < 22; ++c) {
    float wfv = sm[WFo + co * 22 + c];
    float wdv = sm[WDo + co * 22 + c];
#pragma unroll
    for (int v = 0; v < 3; ++v) {
      float4 xv = *(const float4*)&sm[Xo + c * 52 + v * 16 + kq * 4];
      P[v][0] += wfv * xv.x; P[v][1] += wfv * xv.y; P[v][2] += wfv * xv.z; P[v][3] += wfv * xv.w;
      D[v][0] += wdv * xv.x; D[v][1] += wdv * xv.y; D[v][2] += wdv * xv.z; D[v][3] += wdv * xv.w;
    }
  }
  float XO_[3][4];
#pragma unroll
  for (int kk = 0; kk < 4; ++kk) {
    float dot = P[0][kk] * D[0][kk] + P[1][kk] * D[1][kk] + P[2][kk] * D[2][kk];
    float dsq = D[0][kk] * D[0][kk] + D[1][kk] * D[1][kk] + D[2][kk] * D[2][kk];
    float tc = dot / (dsq + 1e-6f);
#pragma unroll
    for (int v = 0; v < 3; ++v) {
      float pv = P[v][kk], dv = D[v][kk];
      float wv = (dot >= 0.f) ? pv : (pv - tc * dv);
      XO_[v][kk] = 0.2f * pv + 0.8f * wv;
    }
  }
#pragma unroll
  for (int v = 0; v < 3; ++v)
    *(float4*)&sm[XOo + co * 52 + v * 16 + kq * 4] =
        make_float4(XO_[v][0], XO_[v][1], XO_[v][2], XO_[v][3]);
  __syncthreads();

  float dp[3][4] = {{0}};
  for (int c2 = 0; c2 < 64; ++c2) {
    float wpv = sm[WPo + co * 65 + c2];
#pragma unroll
    for (int v = 0; v < 3; ++v) {
      float4 xv = *(const float4*)&sm[XOo + c2 * 52 + v * 16 + kq * 4];
      dp[v][0] += wpv * xv.x; dp[v][1] += wpv * xv.y; dp[v][2] += wpv * xv.z; dp[v][3] += wpv * xv.w;
    }
  }
  float4 sc4;
  sc4.x = XO_[0][0] * dp[0][0] + XO_[1][0] * dp[1][0] + XO_[2][0] * dp[2][0];
  sc4.y = XO_[0][1] * dp[0][1] + XO_[1][1] * dp[1][1] + XO_[2][1] * dp[2][1];
  sc4.z = XO_[0][2] * dp[0][2] + XO_[1][2] * dp[1][2] + XO_[2][2] * dp[2][2];
  sc4.w = XO_[0][3] * dp[0][3] + XO_[1][3] * dp[1][3] + XO_[2][3] * dp[2][3];
  *(float4*)&sm[SCo + co * 16 + kq * 4] = sc4;
  __syncthreads();

  if (t < 64) {
    int coo = t;
    float best = sm[SCo + coo * 16];
    int bk = 0;
#pragma unroll
    for (int k = 1; k < 16; ++k) {
      float v = sm[SCo + coo * 16 + k];
      if (v > best) { best = v; bk = k; }  // strict > keeps first index (np.argmax)
    }
#pragma unroll
    for (int v = 0; v < 3; ++v)
      out1[((size_t)(b * 192 + coo * 3 + v)) * 2048 + s] = sm[XOo + coo * 52 + v * 16 + bk];
  }
}

// ---------------------------------------------------------------------------
extern "C" void kernel_launch(void* const* d_in, const int* in_sizes, int n_in,
                              void* d_out, int out_size, void* d_ws, size_t ws_size,
                              hipStream_t stream) {
  const float* xyz = (const float*)d_in[0];     // [8,3,8192]
  const float* points = (const float*)d_in[1];  // [8,63,8192]
  const float* w_feat = (const float*)d_in[2];  // [64,22]
  const float* w_dir = (const float*)d_in[3];   // [64,22]
  const float* w_pool = (const float*)d_in[4];  // [64,64]

  float* out = (float*)d_out;
  float* out0 = out;             // [8,3,2048]
  float* out1 = out + 49152;     // [8,192,2048]
  float* out2 = out + 3194880;   // [8,2048] fps idx as float

  char* ws = (char*)d_ws;
  int* fps_ws = (int*)ws;                   // 16384 ints
  float* nxyz_ws = (float*)(ws + 65536);    // 49152 floats  [B,S,3]
  float* d2_ws = (float*)(ws + 262144);     // 65536 floats  [B,N]
  int* knn_ws = (int*)(ws + 524288);        // 262144 ints   [B,S,16]

  fps_kernel<<<8, 1024, 0, stream>>>(xyz, fps_ws, nxyz_ws, d2_ws, out0, out2);
  knn_kernel<<<4096, 256, 0, stream>>>(xyz, nxyz_ws, d2_ws, knn_ws);
  vn_kernel<<<16384, 256, 0, stream>>>(xyz, points, w_feat, w_dir, w_pool, nxyz_ws,
                                       knn_ws, out1);
}

// Round 14
// 2578.620 us; speedup vs baseline: 1.1529x; 1.0074x over previous
//
#include <hip/hip_runtime.h>
#include <hip/hip_bf16.h>

// Problem constants
// B=8, N=8192, NPOINT=2048, NSAMPLE=16, CIN=22, COUT=64
// outputs: [B,3,2048] (49152) | [B,192,2048] (3145728) | [B,2048] fps idx as float (16384)

typedef float v2f __attribute__((ext_vector_type(2)));
typedef unsigned long long ull;

// ---------------------------------------------------------------------------
// Kernel 1: furthest point sampling (FROZEN at R13 config: 1743 us).
// 1024 threads (16 waves = 4/SIMD), 8 pts/thread; wave-count curve measured
// 2131 (1/SIMD) -> 1884 (2/SIMD) -> 1743 (4/SIMD), flattening => floor.
// Exact NumPy-order f32 arithmetic (contract off) keeps argmax bit-exact.
// ---------------------------------------------------------------------------
__global__ __launch_bounds__(1024) void fps_kernel(
    const float* __restrict__ xyz, int* __restrict__ fps_ws,
    float* __restrict__ nxyz_ws, float* __restrict__ d2_ws,
    float* __restrict__ out0, float* __restrict__ out2) {
#pragma clang fp contract(off)
  const int b = blockIdx.x;
  const int t = threadIdx.x;
  __shared__ float lx[8192], ly[8192], lz[8192];
  __shared__ ull kslot[2];
  __shared__ int hist[2048];
  const float* xb = xyz + (size_t)b * 3 * 8192;

  v2f px[4], py[4], pz[4], dmin[4];
#pragma unroll
  for (int j = 0; j < 4; ++j) {
    int n = j * 2048 + 2 * t;
    px[j] = *(const v2f*)&xb[n];
    py[j] = *(const v2f*)&xb[8192 + n];
    pz[j] = *(const v2f*)&xb[16384 + n];
    dmin[j] = (v2f){1e10f, 1e10f};
    lx[n] = px[j].x; lx[n + 1] = px[j].y;
    ly[n] = py[j].x; ly[n + 1] = py[j].y;
    lz[n] = pz[j].x; lz[n + 1] = pz[j].y;
    // squared norms for the KNN kernel (exactness not critical there)
    v2f sx = px[j] * px[j], sy = py[j] * py[j], sz = pz[j] * pz[j];
    v2f d2 = (sx + sy) + sz;
    *(v2f*)&d2_ws[b * 8192 + n] = d2;
  }
  if (t == 0) { kslot[0] = 0; kslot[1] = 0; }
  int cur = 0;
  __syncthreads();

  for (int it = 0; it < 2048; ++it) {
    float cx = lx[cur], cy = ly[cur], cz = lz[cur];
    if (t == 0) hist[it] = cur;
    v2f bv2 = (v2f){-1.0f, -1.0f};
#pragma unroll
    for (int j = 0; j < 4; ++j) {
      v2f dx = px[j] - cx, dy = py[j] - cy, dz = pz[j] - cz;
      v2f sq = (dx * dx + dy * dy) + dz * dz;  // ((dx^2+dy^2)+dz^2), no FMA
      v2f dm = dmin[j];
      dm.x = fminf(dm.x, sq.x);
      dm.y = fminf(dm.y, sq.y);
      dmin[j] = dm;
      bv2.x = fmaxf(bv2.x, dm.x);
      bv2.y = fmaxf(bv2.y, dm.y);
    }
    float bv = fmaxf(bv2.x, bv2.y);
    unsigned ub = __float_as_uint(bv);  // dist>=0: u32 order == f32 order
    // wave-wide u32 max via DPP (row_shr 1/2/4/8, row_bcast15/31), ans @ lane63
    unsigned m = ub;
#define DPP_U32MAX(ctrl)                                                            \
    {                                                                               \
      unsigned o = (unsigned)__builtin_amdgcn_update_dpp((int)m, (int)m, ctrl, 0xF, 0xF, false); \
      m = (o > m) ? o : m;                                                          \
    }
    DPP_U32MAX(0x111)
    DPP_U32MAX(0x112)
    DPP_U32MAX(0x114)
    DPP_U32MAX(0x118)
    DPP_U32MAX(0x142)
    DPP_U32MAX(0x143)
#undef DPP_U32MAX
    unsigned W = (unsigned)__builtin_amdgcn_readlane((int)m, 63);
    if (ub == W) {
      // winner lane(s): first (lowest) global idx among this thread's 8
      int bn = 0;
#pragma unroll
      for (int j = 3; j >= 0; --j) {
        int n = j * 2048 + 2 * t;
        if (dmin[j].y == bv) bn = n + 1;
        if (dmin[j].x == bv) bn = n;
      }
      ull key = ((ull)(unsigned)(it + 1) << 45) | ((ull)ub << 13) |
                (unsigned)(8191 - bn);
      atomicMax(&kslot[it & 1], key);
    }
    __syncthreads();
    ull g = kslot[it & 1];
    cur = 8191 - (int)((unsigned)g & 0x1FFFu);
  }
  __syncthreads();

  // epilogue: write all outputs from LDS history
  for (int i = t; i < 2048; i += 1024) {
    int idx = hist[i];
    float cx = lx[idx], cy = ly[idx], cz = lz[idx];
    fps_ws[b * 2048 + i] = idx;
    out2[b * 2048 + i] = (float)idx;
    out0[(b * 3 + 0) * 2048 + i] = cx;
    out0[(b * 3 + 1) * 2048 + i] = cy;
    out0[(b * 3 + 2) * 2048 + i] = cz;
    nxyz_ws[(b * 2048 + i) * 3 + 0] = cx;
    nxyz_ws[(b * 2048 + i) * 3 + 1] = cy;
    nxyz_ws[(b * 2048 + i) * 3 + 2] = cz;
  }
}

// ---------------------------------------------------------------------------
// Kernel 2: 16-NN per sampled point. One wave per query; per-lane sorted
// top-16 of 64-bit keys (dist_bits<<32 | idx), then wave-min merge.
// ---------------------------------------------------------------------------
__global__ __launch_bounds__(256) void knn_kernel(
    const float* __restrict__ xyz, const float* __restrict__ nxyz_ws,
    const float* __restrict__ d2_ws, int* __restrict__ knn_ws) {
  const int qid = blockIdx.x * 4 + (threadIdx.x >> 6);
  const int lane = threadIdx.x & 63;
  const int b = qid >> 11;
  const float qx = nxyz_ws[qid * 3], qy = nxyz_ws[qid * 3 + 1], qz = nxyz_ws[qid * 3 + 2];
  const float s2q = qx * qx + qy * qy + qz * qz;
  const float* xb = xyz + (size_t)b * 24576;
  const float* d2b = d2_ws + b * 8192;
  ull arr[16];
#pragma unroll
  for (int j = 0; j < 16; ++j) arr[j] = ~0ull;

  for (int c0 = 0; c0 < 8192; c0 += 64) {
    int n = c0 + lane;
    float x = xb[n], y = xb[8192 + n], z = xb[16384 + n];
    float d2v = d2b[n];
    float dot = qx * x + qy * y + qz * z;
    float dist = (s2q + d2v) - 2.0f * dot;
    unsigned u = __float_as_uint(dist);
    u ^= (unsigned)((int)u >> 31) | 0x80000000u;  // order-preserving flip
    ull key = ((ull)u << 32) | (unsigned)n;
    if (key < arr[15]) {
#pragma unroll
      for (int j = 15; j >= 1; --j)
        arr[j] = (key < arr[j - 1]) ? arr[j - 1] : (arr[j] < key ? arr[j] : key);
      arr[0] = arr[0] < key ? arr[0] : key;
    }
  }
  const int obase = qid * 16;
#pragma unroll 1
  for (int r = 0; r < 16; ++r) {
    ull m = arr[0];
#pragma unroll
    for (int off = 1; off < 64; off <<= 1) {
      ull o = __shfl_xor(m, off);
      m = o < m ? o : m;
    }
    if (lane == r) knn_ws[obase + r] = (int)(unsigned)(m & 0xFFFFFFFFull);
    bool win = (arr[0] == m);
#pragma unroll
    for (int j = 0; j < 15; ++j) arr[j] = win ? arr[j + 1] : arr[j];
    arr[15] = win ? ~0ull : arr[15];
  }
}

// ---------------------------------------------------------------------------
// Kernel 3: fused gather + VNLinearLeakyReLU + VNMaxPool per (b,s).
// v3: w_pool NO LONGER staged in LDS (16.6 KB of identical read-only data per
// block) — read from global (L1-hot after first block per CU). LDS drops
// 50.2 -> 33.5 KB => 4 blocks/CU (was 3), +33% resident waves for latency
// hiding. __launch_bounds__(256,4) pins the occupancy target.
// LDS layout (floats): wf[64*22]@0, wd@1408, x[22*52]@2816, xo[64*52]@3960,
// sc[64*16]@7288  (total 8312 floats = 33.2 KB; all regions keep the same
// mod-32 bank alignment as v1 -> identical conflict profile).
// ---------------------------------------------------------------------------
#define WFo 0
#define WDo 1408
#define Xo 2816
#define XOo 3960
#define SCo 7288
#define SMEM_F 8312

__global__ __launch_bounds__(256, 4) void vn_kernel(
    const float* __restrict__ xyz, const float* __restrict__ points,
    const float* __restrict__ w_feat, const float* __restrict__ w_dir,
    const float* __restrict__ w_pool, const float* __restrict__ nxyz_ws,
    const int* __restrict__ knn_ws, float* __restrict__ out1) {
  __shared__ __align__(16) float sm[SMEM_F];
  __shared__ int ki[16];
  __shared__ float q[3];
  const int bs = blockIdx.x;
  const int b = bs >> 11, s = bs & 2047;
  const int t = threadIdx.x;

  for (int i = t; i < 1408; i += 256) {
    sm[WFo + i] = w_feat[i];
    sm[WDo + i] = w_dir[i];
  }
  if (t < 16) ki[t] = knn_ws[bs * 16 + t];
  if (t < 3) q[t] = nxyz_ws[bs * 3 + t];
  __syncthreads();

  // gather -> x[c][v][k]  (c=0: grouped_xyz - new_xyz; c>=1: points channels)
  for (int e = t; e < 1056; e += 256) {
    int k = e & 15, f = e >> 4;
    int c = f / 3, v = f - 3 * c;
    int n = ki[k];
    float val;
    if (c == 0)
      val = xyz[((size_t)b * 3 + v) * 8192 + n] - q[v];
    else
      val = points[((size_t)b * 63 + 3 * (c - 1) + v) * 8192 + n];
    sm[Xo + c * 52 + v * 16 + k] = val;
  }
  __syncthreads();

  const int co = t >> 2, kq = t & 3;
  float P[3][4] = {{0}}, D[3][4] = {{0}};
  for (int c = 0; c < 22; ++c) {
    float wfv = sm[WFo + co * 22 + c];
    float wdv = sm[WDo + co * 22 + c];
#pragma unroll
    for (int v = 0; v < 3; ++v) {
      float4 xv = *(const float4*)&sm[Xo + c * 52 + v * 16 + kq * 4];
      P[v][0] += wfv * xv.x; P[v][1] += wfv * xv.y; P[v][2] += wfv * xv.z; P[v][3] += wfv * xv.w;
      D[v][0] += wdv * xv.x; D[v][1] += wdv * xv.y; D[v][2] += wdv * xv.z; D[v][3] += wdv * xv.w;
    }
  }
  float XO_[3][4];
#pragma unroll
  for (int kk = 0; kk < 4; ++kk) {
    float dot = P[0][kk] * D[0][kk] + P[1][kk] * D[1][kk] + P[2][kk] * D[2][kk];
    float dsq = D[0][kk] * D[0][kk] + D[1][kk] * D[1][kk] + D[2][kk] * D[2][kk];
    float tc = dot / (dsq + 1e-6f);
#pragma unroll
    for (int v = 0; v < 3; ++v) {
      float pv = P[v][kk], dv = D[v][kk];
      float wv = (dot >= 0.f) ? pv : (pv - tc * dv);
      XO_[v][kk] = 0.2f * pv + 0.8f * wv;
    }
  }
#pragma unroll
  for (int v = 0; v < 3; ++v)
    *(float4*)&sm[XOo + co * 52 + v * 16 + kq * 4] =
        make_float4(XO_[v][0], XO_[v][1], XO_[v][2], XO_[v][3]);
  __syncthreads();

  float dp[3][4] = {{0}};
  for (int c2 = 0; c2 < 64; ++c2) {
    float wpv = w_pool[co * 64 + c2];  // global read, L1-hot, same value x4 threads
#pragma unroll
    for (int v = 0; v < 3; ++v) {
      float4 xv = *(const float4*)&sm[XOo + c2 * 52 + v * 16 + kq * 4];
      dp[v][0] += wpv * xv.x; dp[v][1] += wpv * xv.y; dp[v][2] += wpv * xv.z; dp[v][3] += wpv * xv.w;
    }
  }
  float4 sc4;
  sc4.x = XO_[0][0] * dp[0][0] + XO_[1][0] * dp[1][0] + XO_[2][0] * dp[2][0];
  sc4.y = XO_[0][1] * dp[0][1] + XO_[1][1] * dp[1][1] + XO_[2][1] * dp[2][1];
  sc4.z = XO_[0][2] * dp[0][2] + XO_[1][2] * dp[1][2] + XO_[2][2] * dp[2][2];
  sc4.w = XO_[0][3] * dp[0][3] + XO_[1][3] * dp[1][3] + XO_[2][3] * dp[2][3];
  *(float4*)&sm[SCo + co * 16 + kq * 4] = sc4;
  __syncthreads();

  if (t < 64) {
    int coo = t;
    float best = sm[SCo + coo * 16];
    int bk = 0;
#pragma unroll
    for (int k = 1; k < 16; ++k) {
      float v = sm[SCo + coo * 16 + k];
      if (v > best) { best = v; bk = k; }  // strict > keeps first index (np.argmax)
    }
#pragma unroll
    for (int v = 0; v < 3; ++v)
      out1[((size_t)(b * 192 + coo * 3 + v)) * 2048 + s] = sm[XOo + coo * 52 + v * 16 + bk];
  }
}

// ---------------------------------------------------------------------------
extern "C" void kernel_launch(void* const* d_in, const int* in_sizes, int n_in,
                              void* d_out, int out_size, void* d_ws, size_t ws_size,
                              hipStream_t stream) {
  const float* xyz = (const float*)d_in[0];     // [8,3,8192]
  const float* points = (const float*)d_in[1];  // [8,63,8192]
  const float* w_feat = (const float*)d_in[2];  // [64,22]
  const float* w_dir = (const float*)d_in[3];   // [64,22]
  const float* w_pool = (const float*)d_in[4];  // [64,64]

  float* out = (float*)d_out;
  float* out0 = out;             // [8,3,2048]
  float* out1 = out + 49152;     // [8,192,2048]
  float* out2 = out + 3194880;   // [8,2048] fps idx as float

  char* ws = (char*)d_ws;
  int* fps_ws = (int*)ws;                   // 16384 ints
  float* nxyz_ws = (float*)(ws + 65536);    // 49152 floats  [B,S,3]
  float* d2_ws = (float*)(ws + 262144);     // 65536 floats  [B,N]
  int* knn_ws = (int*)(ws + 524288);        // 262144 ints   [B,S,16]

  fps_kernel<<<8, 1024, 0, stream>>>(xyz, fps_ws, nxyz_ws, d2_ws, out0, out2);
  knn_kernel<<<4096, 256, 0, stream>>>(xyz, nxyz_ws, d2_ws, knn_ws);
  vn_kernel<<<16384, 256, 0, stream>>>(xyz, points, w_feat, w_dir, w_pool, nxyz_ws,
                                       knn_ws, out1);
}